// Round 4
// baseline (488.793 us; speedup 1.0000x reference)
//
#include <hip/hip_runtime.h>

#define HSZ 32
#define SEQ 1024

__device__ __forceinline__ float fast_rcp(float v) { return __builtin_amdgcn_rcpf(v); }

// sigmoid(x) = 1/(1+exp(-x)); exp arg bounded (|g| <~ 12), rcp(inf)=0 saturation is safe.
__device__ __forceinline__ float sigmoidf_(float v) {
    return fast_rcp(1.0f + __expf(-v));
}

// waves_per_eu(2,2): grid is fixed at 2048 waves = 2/SIMD, so occupancy >2 is
// worthless; capping max=2 gives the allocator a 256-VGPR budget so the 64
// W_hh values stay loop-resident instead of spilling (round-3: VGPR=60 + scratch).
__global__ __launch_bounds__(64)
__attribute__((amdgpu_waves_per_eu(2, 2)))
void lstm_attn_fused(const float* __restrict__ x,
                     const float* __restrict__ W_ih,
                     const float* __restrict__ W_hh,
                     const float* __restrict__ b_ih,
                     const float* __restrict__ b_hh,
                     const float* __restrict__ attn_w,
                     const float* __restrict__ fc1_w,
                     const float* __restrict__ fc1_b,
                     const float* __restrict__ fc2_w,
                     const float* __restrict__ fc2_b,
                     float* __restrict__ out)
{
    const int lane = threadIdx.x;        // 0..63
    const int b    = blockIdx.x;         // batch element
    const int row0 = lane;               // rows 0..63  : i (lanes 0..31), f (lanes 32..63)
    const int row1 = lane + 64;          // rows 64..127: g (lanes 0..31), o (lanes 32..63)
    const bool low = lane < HSZ;

    // ---- preload weights into registers ----
    float w0[HSZ], w1[HSZ];
#pragma unroll
    for (int k = 0; k < HSZ; ++k) {
        w0[k] = W_hh[row0 * HSZ + k];
        w1[k] = W_hh[row1 * HSZ + k];
    }
    float wi0x = W_ih[row0 * 3 + 0], wi0y = W_ih[row0 * 3 + 1], wi0z = W_ih[row0 * 3 + 2];
    float wi1x = W_ih[row1 * 3 + 0], wi1y = W_ih[row1 * 3 + 1], wi1z = W_ih[row1 * 3 + 2];
    float bias0 = b_ih[row0] + b_hh[row0];
    float bias1 = b_ih[row1] + b_hh[row1];
    float aw    = attn_w[lane & (HSZ - 1)];

    // Pin loop-invariants: asm defs can't be rematerialized from memory.
#pragma unroll
    for (int k = 0; k < HSZ; ++k) {
        asm volatile("" : "+v"(w0[k]), "+v"(w1[k]));
    }
    asm volatile("" : "+v"(wi0x), "+v"(wi0y), "+v"(wi0z));
    asm volatile("" : "+v"(wi1x), "+v"(wi1y), "+v"(wi1z));
    asm volatile("" : "+v"(bias0), "+v"(bias1), "+v"(aw));

    // v1 nonlinearity: low half -> tanh(g1) = 2*sigmoid(2*g1)-1 ; high half -> sigmoid(g1)
    const float nsS = low ? 2.0f : 1.0f;
    const float nsA = low ? 2.0f : 1.0f;
    const float nsB = low ? -1.0f : 0.0f;

    __shared__ float hsh[HSZ];
    if (low) hsh[lane] = 0.0f;
    __syncthreads();

    float c = 0.0f, h = 0.0f;
    float Pacc = 0.0f, lacc = 0.0f;   // online softmax pooling (scores bounded ~5.7 -> no max tracking)

    const float4* __restrict__ xv = (const float4*)(x + (size_t)b * SEQ * 3);

    auto step = [&](float x0, float x1, float x2) {
        float g0a = fmaf(wi0x, x0, fmaf(wi0y, x1, fmaf(wi0z, x2, bias0)));
        float g1a = fmaf(wi1x, x0, fmaf(wi1y, x1, fmaf(wi1z, x2, bias1)));
        float g0b = 0.0f, g1b = 0.0f;

        // recurrent matvec: h broadcast from LDS (known-good path)
#pragma unroll
        for (int k = 0; k < HSZ; k += 2) {
            const float hk0 = hsh[k];
            const float hk1 = hsh[k + 1];
            g0a = fmaf(w0[k],     hk0, g0a);
            g0b = fmaf(w0[k + 1], hk1, g0b);
            g1a = fmaf(w1[k],     hk0, g1a);
            g1b = fmaf(w1[k + 1], hk1, g1b);
        }
        const float g0 = g0a + g0b;
        const float g1 = g1a + g1b;

        const float v0 = sigmoidf_(g0);                       // i (low) / f (high)
        const float v1 = fmaf(nsA, sigmoidf_(nsS * g1), nsB); // tanh g (low) / o (high)

        const float u0 = __shfl_xor(v0, 32);
        const float u1 = __shfl_xor(v1, 32);
        const float i_ = low ? v0 : u0;
        const float f_ = low ? u0 : v0;
        const float gg = low ? v1 : u1;
        const float o_ = low ? u1 : v1;

        c = fmaf(f_, c, i_ * gg);
        const float tc = fmaf(2.0f, sigmoidf_(2.0f * c), -1.0f);  // tanh(c)
        h = o_ * tc;

        __syncthreads();
        if (low) hsh[lane] = h;
        __syncthreads();

        // attention score: relu(h . attn_w) reduced over 32 units (both halves identical)
        float p = h * aw;
        p += __shfl_xor(p, 1);
        p += __shfl_xor(p, 2);
        p += __shfl_xor(p, 4);
        p += __shfl_xor(p, 8);
        p += __shfl_xor(p, 16);
        p = fmaxf(p, 0.0f);

        const float w = __expf(p);       // bounded by exp(~5.7) ~ 290, fp32-safe over 1024 terms
        lacc += w;
        Pacc = fmaf(w, h, Pacc);
    };

    for (int s0 = 0; s0 < SEQ; s0 += 4) {
        const int fi = (s0 * 3) >> 2;           // float4 index
        const float4 xa = xv[fi + 0];
        const float4 xb = xv[fi + 1];
        const float4 xc = xv[fi + 2];
        step(xa.x, xa.y, xa.z);
        step(xa.w, xb.x, xb.y);
        step(xb.z, xb.w, xc.x);
        step(xc.y, xc.z, xc.w);
    }

    // ---- epilogue: pooled -> fc1(relu) -> fc2 ----
    __syncthreads();
    if (low) hsh[lane] = Pacc / lacc;     // pooled[unit]
    __syncthreads();

    __shared__ float h1sh[16];
    if (lane < 16) {
        float acc = fc1_b[lane];
#pragma unroll
        for (int k = 0; k < HSZ; ++k)
            acc = fmaf(fc1_w[lane * HSZ + k], hsh[k], acc);
        h1sh[lane] = fmaxf(acc, 0.0f);
    }
    __syncthreads();
    if (lane < 2) {
        float acc = fc2_b[lane];
#pragma unroll
        for (int j = 0; j < 16; ++j)
            acc = fmaf(fc2_w[lane * 16 + j], h1sh[j], acc);
        out[b * 2 + lane] = acc;
    }
}

extern "C" void kernel_launch(void* const* d_in, const int* in_sizes, int n_in,
                              void* d_out, int out_size, void* d_ws, size_t ws_size,
                              hipStream_t stream) {
    const float* x      = (const float*)d_in[0];
    const float* W_ih   = (const float*)d_in[1];
    const float* W_hh   = (const float*)d_in[2];
    const float* b_ih   = (const float*)d_in[3];
    const float* b_hh   = (const float*)d_in[4];
    const float* attn_w = (const float*)d_in[5];
    const float* fc1_w  = (const float*)d_in[6];
    const float* fc1_b  = (const float*)d_in[7];
    const float* fc2_w  = (const float*)d_in[8];
    const float* fc2_b  = (const float*)d_in[9];

    const int B = in_sizes[0] / (SEQ * 3);   // 2048

    lstm_attn_fused<<<dim3(B), dim3(64), 0, stream>>>(
        x, W_ih, W_hh, b_ih, b_hh, attn_w, fc1_w, fc1_b, fc2_w, fc2_b,
        (float*)d_out);
}

// Round 5
// 436.946 us; speedup vs baseline: 1.1187x; 1.1187x over previous
//
#include <hip/hip_runtime.h>

#define HSZ 32
#define SEQ 1024

typedef float v2f __attribute__((ext_vector_type(2)));

__device__ __forceinline__ float fast_rcp(float v) { return __builtin_amdgcn_rcpf(v); }

// sigmoid(x) = 1/(1+exp(-x)); exp arg bounded, rcp(inf)=0 saturation is safe.
__device__ __forceinline__ float sigmoidf_(float v) {
    return fast_rcp(1.0f + __expf(-v));
}

// Grid is fixed at 2048 waves = 2/SIMD; cap occupancy at 2 so the allocator
// has a 256-VGPR budget and keeps all invariants resident (r4: VGPR=88, no spill).
__global__ __launch_bounds__(64)
__attribute__((amdgpu_waves_per_eu(2, 2)))
void lstm_attn_fused(const float* __restrict__ x,
                     const float* __restrict__ W_ih,
                     const float* __restrict__ W_hh,
                     const float* __restrict__ b_ih,
                     const float* __restrict__ b_hh,
                     const float* __restrict__ attn_w,
                     const float* __restrict__ fc1_w,
                     const float* __restrict__ fc1_b,
                     const float* __restrict__ fc2_w,
                     const float* __restrict__ fc2_b,
                     float* __restrict__ out)
{
    const int lane = threadIdx.x;        // 0..63
    const int b    = blockIdx.x;         // batch element
    const int row0 = lane;               // rows 0..63  : i (lanes 0..31), f (lanes 32..63)
    const int row1 = lane + 64;          // rows 64..127: g (lanes 0..31), o (lanes 32..63)
    const bool low = lane < HSZ;

    // ---- preload weights as v2 pairs (enables v_pk_fma_f32) ----
    const v2f* __restrict__ Whv = (const v2f*)W_hh;
    const v2f* __restrict__ awp = (const v2f*)attn_w;
    v2f w0[16], w1[16], awv[16];
#pragma unroll
    for (int k = 0; k < 16; ++k) {
        w0[k]  = Whv[row0 * 16 + k];
        w1[k]  = Whv[row1 * 16 + k];
        awv[k] = awp[k];
    }
    float wi0x = W_ih[row0 * 3 + 0], wi0y = W_ih[row0 * 3 + 1], wi0z = W_ih[row0 * 3 + 2];
    float wi1x = W_ih[row1 * 3 + 0], wi1y = W_ih[row1 * 3 + 1], wi1z = W_ih[row1 * 3 + 2];
    float bias0 = b_ih[row0] + b_hh[row0];
    float bias1 = b_ih[row1] + b_hh[row1];

    // Pin loop-invariants: asm defs can't be rematerialized from memory.
#pragma unroll
    for (int k = 0; k < 16; ++k) {
        asm volatile("" : "+v"(w0[k]), "+v"(w1[k]), "+v"(awv[k]));
    }
    asm volatile("" : "+v"(wi0x), "+v"(wi0y), "+v"(wi0z));
    asm volatile("" : "+v"(wi1x), "+v"(wi1y), "+v"(wi1z));
    asm volatile("" : "+v"(bias0), "+v"(bias1));

    // v1 nonlinearity: low half -> tanh(g1) = 2*sigmoid(2*g1)-1 ; high half -> sigmoid(g1)
    const float nsS = low ? 2.0f : 1.0f;
    const float nsA = low ? 2.0f : 1.0f;
    const float nsB = low ? -1.0f : 0.0f;

    __shared__ float4 hsh4[8];           // h broadcast buffer, read as b128
    float* __restrict__ hf = (float*)hsh4;
    if (low) hf[lane] = 0.0f;
    __syncthreads();

    float c = 0.0f, h = 0.0f;
    float Pacc = 0.0f, lacc = 0.0f;      // online softmax pooling (scores bounded ~5.7)

    const float4* __restrict__ xv = (const float4*)(x + (size_t)b * SEQ * 3);

    // One LSTM step. Scores h_prev (the LDS-resident state) in-lane using the
    // same 8 b128 reads the matvec needs; `accum` masks the h0 phantom score.
    auto step = [&](float x0, float x1, float x2, float accum) {
        const float4 q0 = hsh4[0], q1 = hsh4[1], q2 = hsh4[2], q3 = hsh4[3];
        const float4 q4 = hsh4[4], q5 = hsh4[5], q6 = hsh4[6], q7 = hsh4[7];
        const v2f hp[16] = {
            {q0.x,q0.y},{q0.z,q0.w},{q1.x,q1.y},{q1.z,q1.w},
            {q2.x,q2.y},{q2.z,q2.w},{q3.x,q3.y},{q3.z,q3.w},
            {q4.x,q4.y},{q4.z,q4.w},{q5.x,q5.y},{q5.z,q5.w},
            {q6.x,q6.y},{q6.z,q6.w},{q7.x,q7.y},{q7.z,q7.w}};

        v2f a0; a0.x = fmaf(wi0x, x0, fmaf(wi0y, x1, fmaf(wi0z, x2, bias0))); a0.y = 0.0f;
        v2f a1; a1.x = fmaf(wi1x, x0, fmaf(wi1y, x1, fmaf(wi1z, x2, bias1))); a1.y = 0.0f;
        v2f ap; ap.x = 0.0f; ap.y = 0.0f;
#pragma unroll
        for (int k = 0; k < 16; ++k) {
            a0 = __builtin_elementwise_fma(w0[k],  hp[k], a0);
            a1 = __builtin_elementwise_fma(w1[k],  hp[k], a1);
            ap = __builtin_elementwise_fma(awv[k], hp[k], ap);
        }
        const float g0 = a0.x + a0.y;
        const float g1 = a1.x + a1.y;
        const float p  = ap.x + ap.y;    // relu/softmax score of h_prev, same in all lanes

        // attention accumulation for h_prev (this lane's h register still holds it)
        const float wgt = accum * __expf(fmaxf(p, 0.0f));
        lacc += wgt;
        Pacc = fmaf(wgt, h, Pacc);

        const float v0 = sigmoidf_(g0);                       // i (low) / f (high)
        const float v1 = fmaf(nsA, sigmoidf_(nsS * g1), nsB); // tanh g (low) / o (high)

        const float u0 = __shfl_xor(v0, 32);
        const float u1 = __shfl_xor(v1, 32);
        const float i_ = low ? v0 : u0;
        const float f_ = low ? u0 : v0;
        const float gg = low ? v1 : u1;
        const float o_ = low ? u1 : v1;

        c = fmaf(f_, c, i_ * gg);
        const float tc = fmaf(2.0f, sigmoidf_(2.0f * c), -1.0f);  // tanh(c)
        h = o_ * tc;

        __syncthreads();
        if (low) hf[lane] = h;
        __syncthreads();
    };

    // first group: mask the phantom h0 score in slot 0
    {
        const float4 xa = xv[0], xb = xv[1], xc = xv[2];
        step(xa.x, xa.y, xa.z, 0.0f);
        step(xa.w, xb.x, xb.y, 1.0f);
        step(xb.z, xb.w, xc.x, 1.0f);
        step(xc.y, xc.z, xc.w, 1.0f);
    }
    for (int s0 = 4; s0 < SEQ; s0 += 4) {
        const int fi = (s0 * 3) >> 2;
        const float4 xa = xv[fi + 0];
        const float4 xb = xv[fi + 1];
        const float4 xc = xv[fi + 2];
        step(xa.x, xa.y, xa.z, 1.0f);
        step(xa.w, xb.x, xb.y, 1.0f);
        step(xb.z, xb.w, xc.x, 1.0f);
        step(xc.y, xc.z, xc.w, 1.0f);
    }
    // tail: score the final h (written by the last step)
    {
        const float4 q0 = hsh4[0], q1 = hsh4[1], q2 = hsh4[2], q3 = hsh4[3];
        const float4 q4 = hsh4[4], q5 = hsh4[5], q6 = hsh4[6], q7 = hsh4[7];
        const v2f hp[16] = {
            {q0.x,q0.y},{q0.z,q0.w},{q1.x,q1.y},{q1.z,q1.w},
            {q2.x,q2.y},{q2.z,q2.w},{q3.x,q3.y},{q3.z,q3.w},
            {q4.x,q4.y},{q4.z,q4.w},{q5.x,q5.y},{q5.z,q5.w},
            {q6.x,q6.y},{q6.z,q6.w},{q7.x,q7.y},{q7.z,q7.w}};
        v2f ap; ap.x = 0.0f; ap.y = 0.0f;
#pragma unroll
        for (int k = 0; k < 16; ++k)
            ap = __builtin_elementwise_fma(awv[k], hp[k], ap);
        const float p = ap.x + ap.y;
        const float wgt = __expf(fmaxf(p, 0.0f));
        lacc += wgt;
        Pacc = fmaf(wgt, h, Pacc);
    }

    // ---- epilogue: pooled -> fc1(relu) -> fc2 ----
    __syncthreads();
    if (low) hf[lane] = Pacc / lacc;     // pooled[unit]
    __syncthreads();

    __shared__ float h1sh[16];
    if (lane < 16) {
        float acc = fc1_b[lane];
#pragma unroll
        for (int k = 0; k < HSZ; ++k)
            acc = fmaf(fc1_w[lane * HSZ + k], hf[k], acc);
        h1sh[lane] = fmaxf(acc, 0.0f);
    }
    __syncthreads();
    if (lane < 2) {
        float acc = fc2_b[lane];
#pragma unroll
        for (int j = 0; j < 16; ++j)
            acc = fmaf(fc2_w[lane * 16 + j], h1sh[j], acc);
        out[b * 2 + lane] = acc;
    }
}

extern "C" void kernel_launch(void* const* d_in, const int* in_sizes, int n_in,
                              void* d_out, int out_size, void* d_ws, size_t ws_size,
                              hipStream_t stream) {
    const float* x      = (const float*)d_in[0];
    const float* W_ih   = (const float*)d_in[1];
    const float* W_hh   = (const float*)d_in[2];
    const float* b_ih   = (const float*)d_in[3];
    const float* b_hh   = (const float*)d_in[4];
    const float* attn_w = (const float*)d_in[5];
    const float* fc1_w  = (const float*)d_in[6];
    const float* fc1_b  = (const float*)d_in[7];
    const float* fc2_w  = (const float*)d_in[8];
    const float* fc2_b  = (const float*)d_in[9];

    const int B = in_sizes[0] / (SEQ * 3);   // 2048

    lstm_attn_fused<<<dim3(B), dim3(64), 0, stream>>>(
        x, W_ih, W_hh, b_ih, b_hh, attn_w, fc1_w, fc1_b, fc2_w, fc2_b,
        (float*)d_out);
}

// Round 6
// 340.583 us; speedup vs baseline: 1.4352x; 1.2829x over previous
//
#include <hip/hip_runtime.h>

#define HSZ 32
#define SEQ 1024

typedef float v2f __attribute__((ext_vector_type(2)));

__device__ __forceinline__ float fast_rcp(float v) { return __builtin_amdgcn_rcpf(v); }

// sigmoid(x) = 1/(1+exp(-x)); exp args bounded (|g| <~ 10), rcp(inf)=0 saturation safe.
__device__ __forceinline__ float sigmoidf_(float v) {
    return fast_rcp(1.0f + __expf(-v));
}
__device__ __forceinline__ float tanhf_(float v) {
    return fmaf(2.0f, sigmoidf_(2.0f * v), -1.0f);
}

// One wave per block, TWO batch elements per wave (one per 32-lane half).
// Lane u of a half owns rows u,u+32,u+64,u+96 = ALL FOUR gates of unit u:
// no cross-lane gate exchange on the recurrence critical path.
// Grid = B/2 blocks = 1024 waves = exactly 1 wave/SIMD -> occupancy above 1 is
// worthless; waves_per_eu(1,1) gives the allocator the full 512-VGPR budget.
__global__ __launch_bounds__(64)
__attribute__((amdgpu_waves_per_eu(1, 1)))
void lstm_attn_fused(const float* __restrict__ x,
                     const float* __restrict__ W_ih,
                     const float* __restrict__ W_hh,
                     const float* __restrict__ b_ih,
                     const float* __restrict__ b_hh,
                     const float* __restrict__ attn_w,
                     const float* __restrict__ fc1_w,
                     const float* __restrict__ fc1_b,
                     const float* __restrict__ fc2_w,
                     const float* __restrict__ fc2_b,
                     float* __restrict__ out)
{
    const int lane = threadIdx.x;        // 0..63
    const int half = lane >> 5;          // which batch element of this block
    const int u    = lane & 31;          // hidden unit owned by this lane
    const int bsel = blockIdx.x * 2 + half;

    // ---- preload weights: 4 gate rows per lane, v2 packed for v_pk_fma_f32 ----
    const v2f* __restrict__ Whv = (const v2f*)W_hh;      // [128][16] v2f
    const v2f* __restrict__ awp = (const v2f*)attn_w;    // [16] v2f
    v2f wI[16], wF[16], wG[16], wO[16], awv[16];
#pragma unroll
    for (int k = 0; k < 16; ++k) {
        wI[k]  = Whv[(u      ) * 16 + k];
        wF[k]  = Whv[(u + 32 ) * 16 + k];
        wG[k]  = Whv[(u + 64 ) * 16 + k];
        wO[k]  = Whv[(u + 96 ) * 16 + k];
        awv[k] = awp[k];
    }
    float wiI[3], wiF[3], wiG[3], wiO[3];
#pragma unroll
    for (int j = 0; j < 3; ++j) {
        wiI[j] = W_ih[(u      ) * 3 + j];
        wiF[j] = W_ih[(u + 32 ) * 3 + j];
        wiG[j] = W_ih[(u + 64 ) * 3 + j];
        wiO[j] = W_ih[(u + 96 ) * 3 + j];
    }
    float bI = b_ih[u     ] + b_hh[u     ];
    float bF = b_ih[u + 32] + b_hh[u + 32];
    float bG = b_ih[u + 64] + b_hh[u + 64];
    float bO = b_ih[u + 96] + b_hh[u + 96];

    // Pin loop-invariants: asm defs can't be rematerialized from memory.
#pragma unroll
    for (int k = 0; k < 16; ++k) {
        asm volatile("" : "+v"(wI[k]), "+v"(wF[k]), "+v"(wG[k]), "+v"(wO[k]), "+v"(awv[k]));
    }
#pragma unroll
    for (int j = 0; j < 3; ++j) {
        asm volatile("" : "+v"(wiI[j]), "+v"(wiF[j]), "+v"(wiG[j]), "+v"(wiO[j]));
    }
    asm volatile("" : "+v"(bI), "+v"(bF), "+v"(bG), "+v"(bO));

    // h state for both batches: [0..31]=half0, [32..63]=half1 (2 distinct bcast addrs = free)
    __shared__ float4 hbuf4[16];
    float* __restrict__ hbuf = (float*)hbuf4;
    hbuf[lane] = 0.0f;
    __syncthreads();

    float c = 0.0f, h = 0.0f;
    float Pacc = 0.0f, lacc = 0.0f;      // online softmax pooling (scores bounded ~5.7)

    const float4* __restrict__ xv = (const float4*)(x + (size_t)bsel * SEQ * 3);

    auto ldh = [&](v2f hp[16]) {
        const float4* __restrict__ hb = hbuf4 + (half << 3);
        const float4 q0 = hb[0], q1 = hb[1], q2 = hb[2], q3 = hb[3];
        const float4 q4 = hb[4], q5 = hb[5], q6 = hb[6], q7 = hb[7];
        hp[0]={q0.x,q0.y}; hp[1]={q0.z,q0.w}; hp[2]={q1.x,q1.y}; hp[3]={q1.z,q1.w};
        hp[4]={q2.x,q2.y}; hp[5]={q2.z,q2.w}; hp[6]={q3.x,q3.y}; hp[7]={q3.z,q3.w};
        hp[8]={q4.x,q4.y}; hp[9]={q4.z,q4.w}; hp[10]={q5.x,q5.y}; hp[11]={q5.z,q5.w};
        hp[12]={q6.x,q6.y}; hp[13]={q6.z,q6.w}; hp[14]={q7.x,q7.y}; hp[15]={q7.z,q7.w};
    };

    // One LSTM step; scores h_prev in-lane (5th FMA chain), accum masks h0 phantom.
    auto step = [&](float x0, float x1, float x2, float accum) {
        v2f hp[16]; ldh(hp);

        v2f aI; aI.x = fmaf(wiI[0],x0, fmaf(wiI[1],x1, fmaf(wiI[2],x2, bI))); aI.y = 0.0f;
        v2f aF; aF.x = fmaf(wiF[0],x0, fmaf(wiF[1],x1, fmaf(wiF[2],x2, bF))); aF.y = 0.0f;
        v2f aG; aG.x = fmaf(wiG[0],x0, fmaf(wiG[1],x1, fmaf(wiG[2],x2, bG))); aG.y = 0.0f;
        v2f aO; aO.x = fmaf(wiO[0],x0, fmaf(wiO[1],x1, fmaf(wiO[2],x2, bO))); aO.y = 0.0f;
        v2f ap; ap.x = 0.0f; ap.y = 0.0f;
#pragma unroll
        for (int k = 0; k < 16; ++k) {
            aI = __builtin_elementwise_fma(wI[k],  hp[k], aI);
            aF = __builtin_elementwise_fma(wF[k],  hp[k], aF);
            aG = __builtin_elementwise_fma(wG[k],  hp[k], aG);
            aO = __builtin_elementwise_fma(wO[k],  hp[k], aO);
            ap = __builtin_elementwise_fma(awv[k], hp[k], ap);
        }

        // attention accumulation for h_prev (off the recurrence path)
        const float p   = ap.x + ap.y;                    // same in all lanes of the half
        const float wgt = accum * __expf(fmaxf(p, 0.0f));
        lacc += wgt;
        Pacc = fmaf(wgt, h, Pacc);

        // gates -- all lane-local now
        const float i_ = sigmoidf_(aI.x + aI.y);
        const float f_ = sigmoidf_(aF.x + aF.y);
        const float gg = tanhf_   (aG.x + aG.y);
        const float o_ = sigmoidf_(aO.x + aO.y);

        c = fmaf(f_, c, i_ * gg);
        h = o_ * tanhf_(c);

        __syncthreads();
        hbuf[lane] = h;
        __syncthreads();
    };

    // x software pipeline: prefetch next 4-step group while computing current
    float4 xa = xv[0], xb = xv[1], xc = xv[2];
    for (int s0 = 0; s0 < SEQ; s0 += 4) {
        const int nfi = ((s0 + 4) < SEQ) ? (((s0 + 4) * 3) >> 2) : 0;
        const float4 na = xv[nfi], nb = xv[nfi + 1], nc = xv[nfi + 2];
        step(xa.x, xa.y, xa.z, (s0 == 0) ? 0.0f : 1.0f);
        step(xa.w, xb.x, xb.y, 1.0f);
        step(xb.z, xb.w, xc.x, 1.0f);
        step(xc.y, xc.z, xc.w, 1.0f);
        xa = na; xb = nb; xc = nc;
    }
    // tail: score the final h
    {
        v2f hp[16]; ldh(hp);
        v2f ap; ap.x = 0.0f; ap.y = 0.0f;
#pragma unroll
        for (int k = 0; k < 16; ++k)
            ap = __builtin_elementwise_fma(awv[k], hp[k], ap);
        const float p   = ap.x + ap.y;
        const float wgt = __expf(fmaxf(p, 0.0f));
        lacc += wgt;
        Pacc = fmaf(wgt, h, Pacc);
    }

    // ---- epilogue: pooled -> fc1(relu) -> fc2, per half ----
    __syncthreads();
    hbuf[lane] = Pacc / lacc;            // pooled[u] of this half's batch
    __syncthreads();

    float h1 = 0.0f;
    {
        const int j = lane & 15;         // fc1 row (lanes 16..31 compute redundantly)
        const float* __restrict__ hb = hbuf + (half << 5);
        float acc = fc1_b[j];
#pragma unroll
        for (int k = 0; k < HSZ; ++k)
            acc = fmaf(fc1_w[j * HSZ + k], hb[k], acc);
        h1 = fmaxf(acc, 0.0f);
    }
    __shared__ float h1sh[2][16];
    if ((lane & 31) < 16) h1sh[half][lane & 15] = h1;
    __syncthreads();
    if ((lane & 31) < 2) {
        const int oi = lane & 31;
        float acc = fc2_b[oi];
#pragma unroll
        for (int m = 0; m < 16; ++m)
            acc = fmaf(fc2_w[oi * 16 + m], h1sh[half][m], acc);
        out[bsel * 2 + oi] = acc;
    }
}

extern "C" void kernel_launch(void* const* d_in, const int* in_sizes, int n_in,
                              void* d_out, int out_size, void* d_ws, size_t ws_size,
                              hipStream_t stream) {
    const float* x      = (const float*)d_in[0];
    const float* W_ih   = (const float*)d_in[1];
    const float* W_hh   = (const float*)d_in[2];
    const float* b_ih   = (const float*)d_in[3];
    const float* b_hh   = (const float*)d_in[4];
    const float* attn_w = (const float*)d_in[5];
    const float* fc1_w  = (const float*)d_in[6];
    const float* fc1_b  = (const float*)d_in[7];
    const float* fc2_w  = (const float*)d_in[8];
    const float* fc2_b  = (const float*)d_in[9];

    const int B = in_sizes[0] / (SEQ * 3);   // 2048

    lstm_attn_fused<<<dim3(B / 2), dim3(64), 0, stream>>>(
        x, W_ih, W_hh, b_ih, b_hh, attn_w, fc1_w, fc1_b, fc2_w, fc2_b,
        (float*)d_out);
}